// Round 2
// baseline (720.762 us; speedup 1.0000x reference)
//
#include <hip/hip_runtime.h>
#include <hip/hip_bf16.h>
#include <math.h>

// ODE Euler solver with teacher forcing — R5: static-trip-count rewrite.
// Changes vs R4:
//  * run_group templated on NCH (1=solo, 2=pair): ALL nt loops are
//    compile-time -> no runtime `break` inside unrolled loops -> acc
//    arrays provably static-indexed (rule #20: runtime-indexed ext_vector
//    arrays demote to scratch; VGPR_Count=128 in R4 was too small to hold
//    the 128-f32 accumulator set => suspected scratch RMW through L2).
//  * Fully unrolled kt loops (no partial unroll) -> scheduler can hoist
//    weight loads deep (counted vmcnt pipelining).
//  * s_meta via uniform scalar loads (no LDS round-trip / extra barrier).
//  * b2 bias hoisted out of the step loop (step-invariant).

using bf16x8 = __attribute__((ext_vector_type(8))) short;   // 8 bf16
using f32x4  = __attribute__((ext_vector_type(4))) float;   // 4 fp32 acc

constexpr int Bb = 64, Cc = 256, Tt = 64, Vv = 25, Hh = 512;
constexpr int TV = Tt * Vv;              // 1600
constexpr int MAXCH = Bb * (Tt - 1);     // 4032
constexpr int NGRID = 2080;              // >= worst-case group count (2016)

__device__ __forceinline__ short f2bf(float x) {
  union { float f; unsigned u; } v; v.f = x;
  unsigned r = v.u + 0x7FFFu + ((v.u >> 16) & 1u);
  return (short)(r >> 16);
}
__device__ __forceinline__ float fast_tanh(float x) {
  float e = __expf(2.f * x);
  return 1.f - 2.f * __builtin_amdgcn_rcpf(e + 1.f);
}

// ---- fused prepack (blocks 0..1023) + plan (block 1024) ----
// A-frag (16x16x32): lane holds A[m=lane&15][k=(lane>>4)*8+j].
// a1p: A=W1^T (M=H: 32 mt, K=C: 8 kt):  idx ((kt*32+mt)*64+lane)*8+j
// a2p: A=W2^T (M=C: 16 mt, K=H: 16 kt): idx ((kt*16+mt)*64+lane)*8+j
// plan: chains counting-sorted by len desc; hdr = {n1 solos (len>=5), npair}.
__global__ void prep_kernel(const float* __restrict__ W1,
                            const float* __restrict__ W2,
                            const float* __restrict__ tf,
                            short* __restrict__ a1p,
                            short* __restrict__ a2p,
                            int* __restrict__ sorted,
                            int* __restrict__ hdr) {
  if (blockIdx.x < 1024) {
    int idx = blockIdx.x * 256 + threadIdx.x;
    if (idx < 131072) {
      int j = idx & 7, lane = (idx >> 3) & 63, mt = (idx >> 9) & 31, kt = idx >> 14;
      int h = mt * 16 + (lane & 15);
      int c = kt * 32 + (lane >> 4) * 8 + j;
      a1p[idx] = f2bf(W1[c * Hh + h]);
    } else {
      int i2 = idx - 131072;
      int j = i2 & 7, lane = (i2 >> 3) & 63, mt = (i2 >> 9) & 15, kt = i2 >> 13;
      int cm = mt * 16 + (lane & 15);
      int hk = kt * 32 + (lane >> 4) * 8 + j;
      a2p[i2] = f2bf(W2[hk * Cc + cm]);
    }
    return;
  }
  // ---- planning block ----
  __shared__ int cnt[64];
  __shared__ int ofs[64];
  int tid = threadIdx.x;
  if (tid < 64) cnt[tid] = 0;
  for (int i = tid; i < MAXCH; i += 256) sorted[i] = 0;
  __syncthreads();
  if (tid < Bb) {
    int b = tid, prev = 0;
    for (int t = 1; t <= 62; t++)
      if (tf[t * Bb + b] >= 0.5f) { atomicAdd(&cnt[t - prev], 1); prev = t; }
    atomicAdd(&cnt[63 - prev], 1);
  }
  __syncthreads();
  if (tid == 0) {
    int acc = 0;
    for (int l = 63; l >= 1; l--) { ofs[l] = acc; acc += cnt[l]; }
    int n1 = 0;
    for (int l = 5; l <= 63; l++) n1 += cnt[l];
    hdr[0] = n1;                      // solos
    hdr[1] = (acc - n1 + 1) >> 1;     // pairs covering the rest
    hdr[2] = acc;                     // total chains (debug)
    hdr[3] = 0;
  }
  __syncthreads();
  if (tid < Bb) {
    int b = tid, prev = 0;
    for (int t = 1; t <= 62; t++) {
      if (tf[t * Bb + b] >= 0.5f) {
        int len = t - prev;
        int p = atomicAdd(&ofs[len], 1);
        sorted[p] = b | (prev << 6) | (len << 12);
        prev = t;
      }
    }
    int len = 63 - prev;
    int p = atomicAdd(&ofs[len], 1);
    sorted[p] = b | (prev << 6) | (len << 12);
  }
}

// LDS B-frag order (stride fixed at 4 n-tiles):
// elem(k,n) at ((ktile*4 + nt)*64 + (n&15) + 16*((k&31)>>3))*8 + (k&7)
template<int NCH>
__device__ __forceinline__ void run_group(
    int start,
    const float* __restrict__ hsrc, const float* __restrict__ b1,
    const float* __restrict__ b2,   const short* __restrict__ a1p,
    const short* __restrict__ a2p,  const int* __restrict__ sorted,
    float* __restrict__ out, short* __restrict__ zB, short* __restrict__ uB) {
  constexpr int NTA = NCH * 2;                  // n-tiles (16 cols each)
  const int tid  = threadIdx.x;
  const int lane = tid & 63;
  const int w    = tid >> 6;                    // 0..3
  const int m16  = lane & 15;
  const int quad = lane >> 4;

  int meta[NCH], len[NCH];
  #pragma unroll
  for (int j = 0; j < NCH; j++) {
    meta[j] = sorted[start + j];                // block-uniform -> s_load
    len[j]  = (meta[j] >> 12) & 63;
  }
  const int maxlen = len[0];                    // sorted desc

  f32x4 acc2[4][NTA];                           // fp32 master state
  int   obase[4][NTA];

  // ---- init: z0 = h[b,:,t0,:]; write zB in B-frag order ----
  #pragma unroll
  for (int i = 0; i < 4; i++) {
    const int cbase = (w * 4 + i) * 16 + quad * 4;    // 0..255, mult of 4
    const int ktz = cbase >> 5;
    const int gq  = (cbase >> 3) & 3;
    const int j0  = cbase & 7;
    #pragma unroll
    for (int nt = 0; nt < NTA; nt++) {
      const int j  = nt >> 1;
      const int bj = meta[j] & 63, t0 = (meta[j] >> 6) & 63;
      const int v  = (nt & 1) * 16 + m16;
      const bool valid = (len[j] > 0) && (v < Vv);
      const int hb = ((bj * Cc + cbase) * Tt + t0) * Vv + v;
      f32x4 z;
      #pragma unroll
      for (int r = 0; r < 4; r++) z[r] = valid ? hsrc[hb + r * TV] : 0.f;
      acc2[i][nt] = z;
      obase[i][nt] = hb;
      short4 zh;
      zh.x = f2bf(z[0]); zh.y = f2bf(z[1]); zh.z = f2bf(z[2]); zh.w = f2bf(z[3]);
      *(short4*)&zB[((ktz * 4 + nt) * 64 + m16 + 16 * gq) * 8 + j0] = zh;
      if (valid && t0 == 0) {
        #pragma unroll
        for (int r = 0; r < 4; r++) out[hb + r * TV] = z[r];
      }
    }
  }
  __syncthreads();

  // step-invariant b2 bias in registers
  f32x4 b2v[4];
  #pragma unroll
  for (int i = 0; i < 4; i++) {
    const float4 t = *(const float4*)(b2 + (w * 4 + i) * 16 + quad * 4);
    b2v[i] = (f32x4){t.x, t.y, t.z, t.w};
  }

  // mm1 chunk: a1 += W1[:,chunk]^T z   (4 mtiles/wave per bz read)
  auto MM1 = [&](int chunk, f32x4 (&a1)[4][NTA]) {
    #pragma unroll
    for (int kt = 0; kt < 8; kt++) {
      const short* ab = a1p + ((kt * 32 + chunk * 16 + w * 4) * 64 + lane) * 8;
      bf16x8 af0 = *(const bf16x8*)ab;
      bf16x8 af1 = *(const bf16x8*)(ab + 512);
      bf16x8 af2 = *(const bf16x8*)(ab + 1024);
      bf16x8 af3 = *(const bf16x8*)(ab + 1536);
      #pragma unroll
      for (int nt = 0; nt < NTA; nt++) {
        bf16x8 bz = *(const bf16x8*)&zB[((kt * 4 + nt) * 64 + lane) * 8];
        a1[0][nt] = __builtin_amdgcn_mfma_f32_16x16x32_bf16(af0, bz, a1[0][nt], 0, 0, 0);
        a1[1][nt] = __builtin_amdgcn_mfma_f32_16x16x32_bf16(af1, bz, a1[1][nt], 0, 0, 0);
        a1[2][nt] = __builtin_amdgcn_mfma_f32_16x16x32_bf16(af2, bz, a1[2][nt], 0, 0, 0);
        a1[3][nt] = __builtin_amdgcn_mfma_f32_16x16x32_bf16(af3, bz, a1[3][nt], 0, 0, 0);
      }
    }
  };

  // u epilogue -> uB (B-frag order, chunk-local K)
  auto UEPI = [&](int chunk, f32x4 (&a1)[4][NTA]) {
    #pragma unroll
    for (int i = 0; i < 4; i++) {
      const int hl  = (w * 4 + i) * 16 + quad * 4;   // chunk-local h
      const int ktl = hl >> 5;
      const int gq  = (hl >> 3) & 3;
      const int j0  = hl & 7;
      const float4 b1v = *(const float4*)(b1 + chunk * 256 + hl);
      #pragma unroll
      for (int nt = 0; nt < NTA; nt++) {
        short4 up;
        up.x = f2bf(fast_tanh(a1[i][nt][0] + b1v.x));
        up.y = f2bf(fast_tanh(a1[i][nt][1] + b1v.y));
        up.z = f2bf(fast_tanh(a1[i][nt][2] + b1v.z));
        up.w = f2bf(fast_tanh(a1[i][nt][3] + b1v.w));
        *(short4*)&uB[((ktl * 4 + nt) * 64 + m16 + 16 * gq) * 8 + j0] = up;
      }
    }
  };

  // mm2 partial: acc2 += W2[chunk]^T u   (4 mtiles/wave per bu read)
  auto MM2 = [&](int chunk) {
    #pragma unroll
    for (int ktl = 0; ktl < 8; ktl++) {
      const short* ab = a2p + (((chunk * 8 + ktl) * 16 + w * 4) * 64 + lane) * 8;
      bf16x8 af0 = *(const bf16x8*)ab;
      bf16x8 af1 = *(const bf16x8*)(ab + 512);
      bf16x8 af2 = *(const bf16x8*)(ab + 1024);
      bf16x8 af3 = *(const bf16x8*)(ab + 1536);
      #pragma unroll
      for (int nt = 0; nt < NTA; nt++) {
        bf16x8 bu = *(const bf16x8*)&uB[((ktl * 4 + nt) * 64 + lane) * 8];
        acc2[0][nt] = __builtin_amdgcn_mfma_f32_16x16x32_bf16(af0, bu, acc2[0][nt], 0, 0, 0);
        acc2[1][nt] = __builtin_amdgcn_mfma_f32_16x16x32_bf16(af1, bu, acc2[1][nt], 0, 0, 0);
        acc2[2][nt] = __builtin_amdgcn_mfma_f32_16x16x32_bf16(af2, bu, acc2[2][nt], 0, 0, 0);
        acc2[3][nt] = __builtin_amdgcn_mfma_f32_16x16x32_bf16(af3, bu, acc2[3][nt], 0, 0, 0);
      }
    }
  };

  // ---- step loop: 4 barriers/step ----
  for (int s = 0; s < maxlen; s++) {
    #pragma unroll
    for (int i = 0; i < 4; i++)
      #pragma unroll
      for (int nt = 0; nt < NTA; nt++) {
        acc2[i][nt][0] += b2v[i][0]; acc2[i][nt][1] += b2v[i][1];
        acc2[i][nt][2] += b2v[i][2]; acc2[i][nt][3] += b2v[i][3];
      }

    f32x4 acc1[4][NTA];
    #pragma unroll
    for (int i = 0; i < 4; i++)
      #pragma unroll
      for (int nt = 0; nt < NTA; nt++) acc1[i][nt] = (f32x4){0.f, 0.f, 0.f, 0.f};
    MM1(0, acc1);
    UEPI(0, acc1);     // safe: prev step's uB readers done at barrier D
    __syncthreads();   // A: uB(ch0) visible
    MM2(0);
    #pragma unroll
    for (int i = 0; i < 4; i++)
      #pragma unroll
      for (int nt = 0; nt < NTA; nt++) acc1[i][nt] = (f32x4){0.f, 0.f, 0.f, 0.f};
    MM1(1, acc1);      // independent of uB -> overlaps mm2(ch0) region
    __syncthreads();   // B: all mm2(ch0) uB reads done
    UEPI(1, acc1);
    __syncthreads();   // C: uB(ch1) visible
    MM2(1);
    // ---- z epilogue: refresh zB, store alive cols ----
    #pragma unroll
    for (int i = 0; i < 4; i++) {
      const int cbase = (w * 4 + i) * 16 + quad * 4;
      const int ktz = cbase >> 5;
      const int gq  = (cbase >> 3) & 3;
      const int j0  = cbase & 7;
      #pragma unroll
      for (int nt = 0; nt < NTA; nt++) {
        short4 zh;
        zh.x = f2bf(acc2[i][nt][0]); zh.y = f2bf(acc2[i][nt][1]);
        zh.z = f2bf(acc2[i][nt][2]); zh.w = f2bf(acc2[i][nt][3]);
        *(short4*)&zB[((ktz * 4 + nt) * 64 + m16 + 16 * gq) * 8 + j0] = zh;
        const int v = (nt & 1) * 16 + m16;
        if (v < Vv && s < len[nt >> 1]) {
          const int o = obase[i][nt] + (s + 1) * Vv;
          out[o]          = acc2[i][nt][0];
          out[o + TV]     = acc2[i][nt][1];
          out[o + 2 * TV] = acc2[i][nt][2];
          out[o + 3 * TV] = acc2[i][nt][3];
        }
      }
    }
    __syncthreads();   // D: zB ready for next step
  }
}

__global__ __launch_bounds__(256, 2) void group_kernel(
    const float* __restrict__ hsrc, const float* __restrict__ b1,
    const float* __restrict__ b2,   const short* __restrict__ a1p,
    const short* __restrict__ a2p,  const int* __restrict__ sorted,
    const int* __restrict__ hdr,    float* __restrict__ out) {
  __shared__ __align__(16) short zB[8 * 4 * 64 * 8];   // 32 KB (K=256)
  __shared__ __align__(16) short uB[8 * 4 * 64 * 8];   // 32 KB (K-chunk=256)

  const int n1 = hdr[0], npair = hdr[1];
  const int bi = blockIdx.x;
  if (bi < n1) {
    run_group<1>(bi, hsrc, b1, b2, a1p, a2p, sorted, out, zB, uB);
  } else if (bi < n1 + npair) {
    run_group<2>(n1 + (bi - n1) * 2, hsrc, b1, b2, a1p, a2p, sorted, out, zB, uB);
  }
}

extern "C" void kernel_launch(void* const* d_in, const int* in_sizes, int n_in,
                              void* d_out, int out_size, void* d_ws, size_t ws_size,
                              hipStream_t stream) {
  const float* h_ptr = (const float*)d_in[0];
  const float* W1    = (const float*)d_in[1];
  const float* b1    = (const float*)d_in[2];
  const float* W2    = (const float*)d_in[3];
  const float* b2    = (const float*)d_in[4];
  const float* tf    = (const float*)d_in[5];
  float* out = (float*)d_out;

  short* a1p  = (short*)d_ws;            // 256 KB
  short* a2p  = a1p + 131072;            // 256 KB
  int* sorted = (int*)(a2p + 131072);    // 16 KB
  int* hdr    = sorted + MAXCH;          // 16 B

  prep_kernel<<<1025, 256, 0, stream>>>(W1, W2, tf, a1p, a2p, sorted, hdr);
  group_kernel<<<NGRID, 256, 0, stream>>>(h_ptr, b1, b2, a1p, a2p, sorted, hdr, out);
}

// Round 3
// 681.961 us; speedup vs baseline: 1.0569x; 1.0569x over previous
//
#include <hip/hip_runtime.h>
#include <hip/hip_bf16.h>
#include <math.h>

// ODE Euler solver with teacher forcing — R6: occupancy attack.
// Changes vs R5/R4:
//  * 512-thread blocks (8 waves, 2 mtiles/wave) with the SAME 64.5 KB LDS
//    -> 2 blocks/CU = 16 waves/CU (R3/R4 both had 8). Doubles TLP.
//  * Accumulator set halves (acc1+acc2 = 64 f32/lane) -> fits the 128-VGPR
//    budget of __launch_bounds__(512,4); keeps R5's fully-static NCH
//    template (verified correct) WITHOUT the R5 spill (R5: +1.1 GB/dispatch
//    scratch traffic at 128-reg cap; FETCH 670/WRITE 691 MB).
//  * Same 4-barrier step schedule, same verified MFMA fragment layouts.

using bf16x8 = __attribute__((ext_vector_type(8))) short;   // 8 bf16
using f32x4  = __attribute__((ext_vector_type(4))) float;   // 4 fp32 acc

constexpr int Bb = 64, Cc = 256, Tt = 64, Vv = 25, Hh = 512;
constexpr int TV = Tt * Vv;              // 1600
constexpr int MAXCH = Bb * (Tt - 1);     // 4032
constexpr int NGRID = 2080;              // >= worst-case group count (2016)

__device__ __forceinline__ short f2bf(float x) {
  union { float f; unsigned u; } v; v.f = x;
  unsigned r = v.u + 0x7FFFu + ((v.u >> 16) & 1u);
  return (short)(r >> 16);
}
__device__ __forceinline__ float fast_tanh(float x) {
  float e = __expf(2.f * x);
  return 1.f - 2.f * __builtin_amdgcn_rcpf(e + 1.f);
}

// ---- fused prepack (blocks 0..1023) + plan (block 1024) ----
// A-frag (16x16x32): lane holds A[m=lane&15][k=(lane>>4)*8+j].
// a1p: A=W1^T (M=H: 32 mt, K=C: 8 kt):  idx ((kt*32+mt)*64+lane)*8+j
// a2p: A=W2^T (M=C: 16 mt, K=H: 16 kt): idx ((kt*16+mt)*64+lane)*8+j
// plan: chains counting-sorted by len desc; hdr = {n1 solos (len>=5), npair}.
__global__ void prep_kernel(const float* __restrict__ W1,
                            const float* __restrict__ W2,
                            const float* __restrict__ tf,
                            short* __restrict__ a1p,
                            short* __restrict__ a2p,
                            int* __restrict__ sorted,
                            int* __restrict__ hdr) {
  if (blockIdx.x < 1024) {
    int idx = blockIdx.x * 256 + threadIdx.x;
    if (idx < 131072) {
      int j = idx & 7, lane = (idx >> 3) & 63, mt = (idx >> 9) & 31, kt = idx >> 14;
      int h = mt * 16 + (lane & 15);
      int c = kt * 32 + (lane >> 4) * 8 + j;
      a1p[idx] = f2bf(W1[c * Hh + h]);
    } else {
      int i2 = idx - 131072;
      int j = i2 & 7, lane = (i2 >> 3) & 63, mt = (i2 >> 9) & 15, kt = i2 >> 13;
      int cm = mt * 16 + (lane & 15);
      int hk = kt * 32 + (lane >> 4) * 8 + j;
      a2p[i2] = f2bf(W2[hk * Cc + cm]);
    }
    return;
  }
  // ---- planning block ----
  __shared__ int cnt[64];
  __shared__ int ofs[64];
  int tid = threadIdx.x;
  if (tid < 64) cnt[tid] = 0;
  for (int i = tid; i < MAXCH; i += 256) sorted[i] = 0;
  __syncthreads();
  if (tid < Bb) {
    int b = tid, prev = 0;
    for (int t = 1; t <= 62; t++)
      if (tf[t * Bb + b] >= 0.5f) { atomicAdd(&cnt[t - prev], 1); prev = t; }
    atomicAdd(&cnt[63 - prev], 1);
  }
  __syncthreads();
  if (tid == 0) {
    int acc = 0;
    for (int l = 63; l >= 1; l--) { ofs[l] = acc; acc += cnt[l]; }
    int n1 = 0;
    for (int l = 5; l <= 63; l++) n1 += cnt[l];
    hdr[0] = n1;                      // solos
    hdr[1] = (acc - n1 + 1) >> 1;     // pairs covering the rest
    hdr[2] = acc;                     // total chains (debug)
    hdr[3] = 0;
  }
  __syncthreads();
  if (tid < Bb) {
    int b = tid, prev = 0;
    for (int t = 1; t <= 62; t++) {
      if (tf[t * Bb + b] >= 0.5f) {
        int len = t - prev;
        int p = atomicAdd(&ofs[len], 1);
        sorted[p] = b | (prev << 6) | (len << 12);
        prev = t;
      }
    }
    int len = 63 - prev;
    int p = atomicAdd(&ofs[len], 1);
    sorted[p] = b | (prev << 6) | (len << 12);
  }
}

// LDS B-frag order (stride fixed at 4 n-tiles):
// elem(k,n) at ((ktile*4 + nt)*64 + (n&15) + 16*((k&31)>>3))*8 + (k&7)
template<int NCH>
__device__ __forceinline__ void run_group(
    int start,
    const float* __restrict__ hsrc, const float* __restrict__ b1,
    const float* __restrict__ b2,   const short* __restrict__ a1p,
    const short* __restrict__ a2p,  const int* __restrict__ sorted,
    float* __restrict__ out, short* __restrict__ zB, short* __restrict__ uB) {
  constexpr int NTA = NCH * 2;                  // n-tiles (16 cols each)
  const int tid  = threadIdx.x;
  const int lane = tid & 63;
  const int w    = tid >> 6;                    // 0..7
  const int m16  = lane & 15;
  const int quad = lane >> 4;

  int meta[NCH], len[NCH];
  #pragma unroll
  for (int j = 0; j < NCH; j++) {
    meta[j] = sorted[start + j];                // block-uniform -> s_load
    len[j]  = (meta[j] >> 12) & 63;
  }
  const int maxlen = len[0];                    // sorted desc

  f32x4 acc2[2][NTA];                           // fp32 master state
  int   obase[2][NTA];

  // ---- init: z0 = h[b,:,t0,:]; write zB in B-frag order ----
  #pragma unroll
  for (int i = 0; i < 2; i++) {
    const int cbase = (w * 2 + i) * 16 + quad * 4;    // 0..255, mult of 4
    const int ktz = cbase >> 5;
    const int gq  = (cbase >> 3) & 3;
    const int j0  = cbase & 7;
    #pragma unroll
    for (int nt = 0; nt < NTA; nt++) {
      const int j  = nt >> 1;
      const int bj = meta[j] & 63, t0 = (meta[j] >> 6) & 63;
      const int v  = (nt & 1) * 16 + m16;
      const bool valid = (len[j] > 0) && (v < Vv);
      const int hb = ((bj * Cc + cbase) * Tt + t0) * Vv + v;
      f32x4 z;
      #pragma unroll
      for (int r = 0; r < 4; r++) z[r] = valid ? hsrc[hb + r * TV] : 0.f;
      acc2[i][nt] = z;
      obase[i][nt] = hb;
      short4 zh;
      zh.x = f2bf(z[0]); zh.y = f2bf(z[1]); zh.z = f2bf(z[2]); zh.w = f2bf(z[3]);
      *(short4*)&zB[((ktz * 4 + nt) * 64 + m16 + 16 * gq) * 8 + j0] = zh;
      if (valid && t0 == 0) {
        #pragma unroll
        for (int r = 0; r < 4; r++) out[hb + r * TV] = z[r];
      }
    }
  }
  __syncthreads();

  // step-invariant b2 bias in registers
  f32x4 b2v[2];
  #pragma unroll
  for (int i = 0; i < 2; i++) {
    const float4 t = *(const float4*)(b2 + (w * 2 + i) * 16 + quad * 4);
    b2v[i] = (f32x4){t.x, t.y, t.z, t.w};
  }

  // mm1 chunk: a1 += W1[:,chunk]^T z   (2 mtiles/wave per bz read)
  auto MM1 = [&](int chunk, f32x4 (&a1)[2][NTA]) {
    #pragma unroll
    for (int kt = 0; kt < 8; kt++) {
      const short* ab = a1p + ((kt * 32 + chunk * 16 + w * 2) * 64 + lane) * 8;
      bf16x8 af0 = *(const bf16x8*)ab;
      bf16x8 af1 = *(const bf16x8*)(ab + 512);
      #pragma unroll
      for (int nt = 0; nt < NTA; nt++) {
        bf16x8 bz = *(const bf16x8*)&zB[((kt * 4 + nt) * 64 + lane) * 8];
        a1[0][nt] = __builtin_amdgcn_mfma_f32_16x16x32_bf16(af0, bz, a1[0][nt], 0, 0, 0);
        a1[1][nt] = __builtin_amdgcn_mfma_f32_16x16x32_bf16(af1, bz, a1[1][nt], 0, 0, 0);
      }
    }
  };

  // u epilogue -> uB (B-frag order, chunk-local K)
  auto UEPI = [&](int chunk, f32x4 (&a1)[2][NTA]) {
    #pragma unroll
    for (int i = 0; i < 2; i++) {
      const int hl  = (w * 2 + i) * 16 + quad * 4;   // chunk-local h
      const int ktl = hl >> 5;
      const int gq  = (hl >> 3) & 3;
      const int j0  = hl & 7;
      const float4 b1v = *(const float4*)(b1 + chunk * 256 + hl);
      #pragma unroll
      for (int nt = 0; nt < NTA; nt++) {
        short4 up;
        up.x = f2bf(fast_tanh(a1[i][nt][0] + b1v.x));
        up.y = f2bf(fast_tanh(a1[i][nt][1] + b1v.y));
        up.z = f2bf(fast_tanh(a1[i][nt][2] + b1v.z));
        up.w = f2bf(fast_tanh(a1[i][nt][3] + b1v.w));
        *(short4*)&uB[((ktl * 4 + nt) * 64 + m16 + 16 * gq) * 8 + j0] = up;
      }
    }
  };

  // mm2 partial: acc2 += W2[chunk]^T u   (2 mtiles/wave per bu read)
  auto MM2 = [&](int chunk) {
    #pragma unroll
    for (int ktl = 0; ktl < 8; ktl++) {
      const short* ab = a2p + (((chunk * 8 + ktl) * 16 + w * 2) * 64 + lane) * 8;
      bf16x8 af0 = *(const bf16x8*)ab;
      bf16x8 af1 = *(const bf16x8*)(ab + 512);
      #pragma unroll
      for (int nt = 0; nt < NTA; nt++) {
        bf16x8 bu = *(const bf16x8*)&uB[((ktl * 4 + nt) * 64 + lane) * 8];
        acc2[0][nt] = __builtin_amdgcn_mfma_f32_16x16x32_bf16(af0, bu, acc2[0][nt], 0, 0, 0);
        acc2[1][nt] = __builtin_amdgcn_mfma_f32_16x16x32_bf16(af1, bu, acc2[1][nt], 0, 0, 0);
      }
    }
  };

  // ---- step loop: 4 barriers/step ----
  for (int s = 0; s < maxlen; s++) {
    #pragma unroll
    for (int i = 0; i < 2; i++)
      #pragma unroll
      for (int nt = 0; nt < NTA; nt++) {
        acc2[i][nt][0] += b2v[i][0]; acc2[i][nt][1] += b2v[i][1];
        acc2[i][nt][2] += b2v[i][2]; acc2[i][nt][3] += b2v[i][3];
      }

    f32x4 acc1[2][NTA];
    #pragma unroll
    for (int i = 0; i < 2; i++)
      #pragma unroll
      for (int nt = 0; nt < NTA; nt++) acc1[i][nt] = (f32x4){0.f, 0.f, 0.f, 0.f};
    MM1(0, acc1);
    UEPI(0, acc1);     // safe: prev step's uB readers done at barrier D
    __syncthreads();   // A: uB(ch0) visible
    MM2(0);
    #pragma unroll
    for (int i = 0; i < 2; i++)
      #pragma unroll
      for (int nt = 0; nt < NTA; nt++) acc1[i][nt] = (f32x4){0.f, 0.f, 0.f, 0.f};
    MM1(1, acc1);      // independent of uB -> overlaps mm2(ch0) region
    __syncthreads();   // B: all mm2(ch0) uB reads done
    UEPI(1, acc1);
    __syncthreads();   // C: uB(ch1) visible
    MM2(1);
    // ---- z epilogue: refresh zB, store alive cols ----
    #pragma unroll
    for (int i = 0; i < 2; i++) {
      const int cbase = (w * 2 + i) * 16 + quad * 4;
      const int ktz = cbase >> 5;
      const int gq  = (cbase >> 3) & 3;
      const int j0  = cbase & 7;
      #pragma unroll
      for (int nt = 0; nt < NTA; nt++) {
        short4 zh;
        zh.x = f2bf(acc2[i][nt][0]); zh.y = f2bf(acc2[i][nt][1]);
        zh.z = f2bf(acc2[i][nt][2]); zh.w = f2bf(acc2[i][nt][3]);
        *(short4*)&zB[((ktz * 4 + nt) * 64 + m16 + 16 * gq) * 8 + j0] = zh;
        const int v = (nt & 1) * 16 + m16;
        if (v < Vv && s < len[nt >> 1]) {
          const int o = obase[i][nt] + (s + 1) * Vv;
          out[o]          = acc2[i][nt][0];
          out[o + TV]     = acc2[i][nt][1];
          out[o + 2 * TV] = acc2[i][nt][2];
          out[o + 3 * TV] = acc2[i][nt][3];
        }
      }
    }
    __syncthreads();   // D: zB ready for next step
  }
}

__global__ __launch_bounds__(512, 4) void group_kernel(
    const float* __restrict__ hsrc, const float* __restrict__ b1,
    const float* __restrict__ b2,   const short* __restrict__ a1p,
    const short* __restrict__ a2p,  const int* __restrict__ sorted,
    const int* __restrict__ hdr,    float* __restrict__ out) {
  __shared__ __align__(16) short zB[8 * 4 * 64 * 8];   // 32 KB (K=256)
  __shared__ __align__(16) short uB[8 * 4 * 64 * 8];   // 32 KB (K-chunk=256)

  const int n1 = hdr[0], npair = hdr[1];
  const int bi = blockIdx.x;
  if (bi < n1) {
    run_group<1>(bi, hsrc, b1, b2, a1p, a2p, sorted, out, zB, uB);
  } else if (bi < n1 + npair) {
    run_group<2>(n1 + (bi - n1) * 2, hsrc, b1, b2, a1p, a2p, sorted, out, zB, uB);
  }
}

extern "C" void kernel_launch(void* const* d_in, const int* in_sizes, int n_in,
                              void* d_out, int out_size, void* d_ws, size_t ws_size,
                              hipStream_t stream) {
  const float* h_ptr = (const float*)d_in[0];
  const float* W1    = (const float*)d_in[1];
  const float* b1    = (const float*)d_in[2];
  const float* W2    = (const float*)d_in[3];
  const float* b2    = (const float*)d_in[4];
  const float* tf    = (const float*)d_in[5];
  float* out = (float*)d_out;

  short* a1p  = (short*)d_ws;            // 256 KB
  short* a2p  = a1p + 131072;            // 256 KB
  int* sorted = (int*)(a2p + 131072);    // 16 KB
  int* hdr    = sorted + MAXCH;          // 16 B

  prep_kernel<<<1025, 256, 0, stream>>>(W1, W2, tf, a1p, a2p, sorted, hdr);
  group_kernel<<<NGRID, 512, 0, stream>>>(h_ptr, b1, b2, a1p, a2p, sorted, hdr, out);
}

// Round 5
// 496.358 us; speedup vs baseline: 1.4521x; 1.3739x over previous
//
#include <hip/hip_runtime.h>
#include <hip/hip_bf16.h>
#include <math.h>

// ODE Euler solver with teacher forcing — R8 (= R7 resubmit; R7 bench was an
// infra failure: container acquire/push flake, no kernel diagnostic).
// Evidence: R3 (128col/512thr/5bar) = 179us ~= R4 (64col/256thr/4bar) = 185us.
// The invariant across both: ~2.4k block-steps x 512KB weight re-stream from L2
// + full vmcnt(0) drain at every __syncthreads. Changes:
//  * Uniform quads: ALWAYS 4 chains/block (NT=8, 128 cols), sorted desc ->
//    Sigma block-steps ~2400 -> ~1200 -> weight traffic halves.
//  * lgkm-only barriers (raw s_barrier + s_waitcnt lgkmcnt(0)): LDS deps are the
//    only cross-wave deps in the step loop; weight loads + out stores stay in
//    flight across barriers (T4: never vmcnt(0) in main loop).
//  * s_setprio(1) around MFMA clusters (T5).
//  * __launch_bounds__(512,2) -> 256-reg cap (R6's (512,4) forced 128 -> spill).
//  * acc1+acc2 = 128 f32/lane (R4-proven no-spill density), 2 mt/wave.

using bf16x8 = __attribute__((ext_vector_type(8))) short;   // 8 bf16
using f32x4  = __attribute__((ext_vector_type(4))) float;   // 4 fp32 acc

constexpr int Bb = 64, Cc = 256, Tt = 64, Vv = 25, Hh = 512;
constexpr int TV = Tt * Vv;              // 1600
constexpr int MAXCH = Bb * (Tt - 1);     // 4032
constexpr int NGRID = 1008;              // ceil(MAXCH/4)

__device__ __forceinline__ short f2bf(float x) {
  union { float f; unsigned u; } v; v.f = x;
  unsigned r = v.u + 0x7FFFu + ((v.u >> 16) & 1u);
  return (short)(r >> 16);
}
__device__ __forceinline__ float fast_tanh(float x) {
  float e = __expf(2.f * x);
  return 1.f - 2.f * __builtin_amdgcn_rcpf(e + 1.f);
}
// Barrier that drains ONLY LDS (lgkmcnt). Global loads/stores stay in flight.
// asm "memory" clobbers fence the compiler on both sides (LDS ops can't cross).
__device__ __forceinline__ void bar_lds() {
  asm volatile("s_waitcnt lgkmcnt(0)" ::: "memory");
  __builtin_amdgcn_s_barrier();
  asm volatile("" ::: "memory");
}

// ---- fused prepack (blocks 0..1023) + plan (block 1024) ----
// A-frag (16x16x32): lane holds A[m=lane&15][k=(lane>>4)*8+j].
// a1p: A=W1^T (M=H: 32 mt, K=C: 8 kt):  idx ((kt*32+mt)*64+lane)*8+j
// a2p: A=W2^T (M=C: 16 mt, K=H: 16 kt): idx ((kt*16+mt)*64+lane)*8+j
// plan: chains counting-sorted by len desc; blocks take fixed quads.
__global__ void prep_kernel(const float* __restrict__ W1,
                            const float* __restrict__ W2,
                            const float* __restrict__ tf,
                            short* __restrict__ a1p,
                            short* __restrict__ a2p,
                            int* __restrict__ sorted,
                            int* __restrict__ hdr) {
  if (blockIdx.x < 1024) {
    int idx = blockIdx.x * 256 + threadIdx.x;
    if (idx < 131072) {
      int j = idx & 7, lane = (idx >> 3) & 63, mt = (idx >> 9) & 31, kt = idx >> 14;
      int h = mt * 16 + (lane & 15);
      int c = kt * 32 + (lane >> 4) * 8 + j;
      a1p[idx] = f2bf(W1[c * Hh + h]);
    } else {
      int i2 = idx - 131072;
      int j = i2 & 7, lane = (i2 >> 3) & 63, mt = (i2 >> 9) & 15, kt = i2 >> 13;
      int cm = mt * 16 + (lane & 15);
      int hk = kt * 32 + (lane >> 4) * 8 + j;
      a2p[i2] = f2bf(W2[hk * Cc + cm]);
    }
    return;
  }
  // ---- planning block ----
  __shared__ int cnt[64];
  __shared__ int ofs[64];
  int tid = threadIdx.x;
  if (tid < 64) cnt[tid] = 0;
  for (int i = tid; i < MAXCH; i += 256) sorted[i] = 0;
  __syncthreads();
  if (tid < Bb) {
    int b = tid, prev = 0;
    for (int t = 1; t <= 62; t++)
      if (tf[t * Bb + b] >= 0.5f) { atomicAdd(&cnt[t - prev], 1); prev = t; }
    atomicAdd(&cnt[63 - prev], 1);
  }
  __syncthreads();
  if (tid == 0) {
    int acc = 0;
    for (int l = 63; l >= 1; l--) { ofs[l] = acc; acc += cnt[l]; }
    hdr[0] = acc;                     // total chains (debug only)
  }
  __syncthreads();
  if (tid < Bb) {
    int b = tid, prev = 0;
    for (int t = 1; t <= 62; t++) {
      if (tf[t * Bb + b] >= 0.5f) {
        int len = t - prev;
        int p = atomicAdd(&ofs[len], 1);
        sorted[p] = b | (prev << 6) | (len << 12);
        prev = t;
      }
    }
    int len = 63 - prev;
    int p = atomicAdd(&ofs[len], 1);
    sorted[p] = b | (prev << 6) | (len << 12);
  }
}

// ---- Group kernel: 512 threads (8 waves), ALWAYS 4 chains (NT=8) ----
// LDS B-frag order: elem(k,n) at ((ktile*8 + nt)*64 + (n&15) + 16*((k&31)>>3))*8 + (k&7)
__global__ __launch_bounds__(512, 2) void group_kernel(
    const float* __restrict__ hsrc, const float* __restrict__ b1,
    const float* __restrict__ b2,   const short* __restrict__ a1p,
    const short* __restrict__ a2p,  const int* __restrict__ sorted,
    float* __restrict__ out) {
  __shared__ __align__(16) short zB[8 * 8 * 64 * 8];   // 64 KB (K=256, 8 nt)
  __shared__ __align__(16) short uB[8 * 8 * 64 * 8];   // 64 KB (K-chunk=256, 8 nt)

  const int start = blockIdx.x * 4;
  const int tid  = threadIdx.x;
  const int lane = tid & 63;
  const int w    = tid >> 6;                    // 0..7
  const int m16  = lane & 15;
  const int quad = lane >> 4;

  int len4[4], sbase[4], t04[4];                // block-uniform -> SGPRs
  #pragma unroll
  for (int j = 0; j < 4; j++) {
    const int mj = sorted[start + j];
    len4[j]  = (mj >> 12) & 63;
    t04[j]   = (mj >> 6) & 63;
    sbase[j] = (mj & 63) * Cc * TV + t04[j] * Vv;
  }
  const int maxlen = len4[0];                   // sorted desc

  f32x4 acc2[2][8];                             // fp32 master state

  // ---- init: z0 = h[b,:,t0,:]; write zB in B-frag order ----
  #pragma unroll
  for (int i = 0; i < 2; i++) {
    const int cbase = (w * 2 + i) * 16 + quad * 4;    // 0..255, mult of 4
    const int ktz = cbase >> 5;
    const int gq  = (cbase >> 3) & 3;
    const int j0  = cbase & 7;
    #pragma unroll
    for (int nt = 0; nt < 8; nt++) {
      const int j  = nt >> 1;
      const int v  = (nt & 1) * 16 + m16;
      const bool valid = (len4[j] > 0) && (v < Vv);
      const int hb = sbase[j] + cbase * TV + v;
      f32x4 z;
      #pragma unroll
      for (int r = 0; r < 4; r++) z[r] = valid ? hsrc[hb + r * TV] : 0.f;
      acc2[i][nt] = z;
      short4 zh;
      zh.x = f2bf(z[0]); zh.y = f2bf(z[1]); zh.z = f2bf(z[2]); zh.w = f2bf(z[3]);
      *(short4*)&zB[((ktz * 8 + nt) * 64 + m16 + 16 * gq) * 8 + j0] = zh;
      if (valid && t04[j] == 0) {
        #pragma unroll
        for (int r = 0; r < 4; r++) out[hb + r * TV] = z[r];
      }
    }
  }
  bar_lds();

  // step-invariant b2 bias in registers
  f32x4 b2v[2];
  #pragma unroll
  for (int i = 0; i < 2; i++) {
    const float4 t = *(const float4*)(b2 + (w * 2 + i) * 16 + quad * 4);
    b2v[i] = (f32x4){t.x, t.y, t.z, t.w};
  }

  // mm1 chunk: a1 += W1[:,chunk]^T z   (2 mtiles/wave per bz read)
  auto MM1 = [&](int chunk, f32x4 (&a1)[2][8]) {
    __builtin_amdgcn_s_setprio(1);
    #pragma unroll
    for (int kt = 0; kt < 8; kt++) {
      const short* ab = a1p + ((kt * 32 + chunk * 16 + w * 2) * 64 + lane) * 8;
      bf16x8 af0 = *(const bf16x8*)ab;
      bf16x8 af1 = *(const bf16x8*)(ab + 512);
      #pragma unroll
      for (int nt = 0; nt < 8; nt++) {
        bf16x8 bz = *(const bf16x8*)&zB[((kt * 8 + nt) * 64 + lane) * 8];
        a1[0][nt] = __builtin_amdgcn_mfma_f32_16x16x32_bf16(af0, bz, a1[0][nt], 0, 0, 0);
        a1[1][nt] = __builtin_amdgcn_mfma_f32_16x16x32_bf16(af1, bz, a1[1][nt], 0, 0, 0);
      }
    }
    __builtin_amdgcn_s_setprio(0);
  };

  // u epilogue -> uB (B-frag order, chunk-local K)
  auto UEPI = [&](int chunk, f32x4 (&a1)[2][8]) {
    #pragma unroll
    for (int i = 0; i < 2; i++) {
      const int hl  = (w * 2 + i) * 16 + quad * 4;   // chunk-local h
      const int ktl = hl >> 5;
      const int gq  = (hl >> 3) & 3;
      const int j0  = hl & 7;
      const float4 b1v = *(const float4*)(b1 + chunk * 256 + hl);
      #pragma unroll
      for (int nt = 0; nt < 8; nt++) {
        short4 up;
        up.x = f2bf(fast_tanh(a1[i][nt][0] + b1v.x));
        up.y = f2bf(fast_tanh(a1[i][nt][1] + b1v.y));
        up.z = f2bf(fast_tanh(a1[i][nt][2] + b1v.z));
        up.w = f2bf(fast_tanh(a1[i][nt][3] + b1v.w));
        *(short4*)&uB[((ktl * 8 + nt) * 64 + m16 + 16 * gq) * 8 + j0] = up;
      }
    }
  };

  // mm2 partial: acc2 += W2[chunk]^T u   (2 mtiles/wave per bu read)
  auto MM2 = [&](int chunk) {
    __builtin_amdgcn_s_setprio(1);
    #pragma unroll
    for (int ktl = 0; ktl < 8; ktl++) {
      const short* ab = a2p + (((chunk * 8 + ktl) * 16 + w * 2) * 64 + lane) * 8;
      bf16x8 af0 = *(const bf16x8*)ab;
      bf16x8 af1 = *(const bf16x8*)(ab + 512);
      #pragma unroll
      for (int nt = 0; nt < 8; nt++) {
        bf16x8 bu = *(const bf16x8*)&uB[((ktl * 8 + nt) * 64 + lane) * 8];
        acc2[0][nt] = __builtin_amdgcn_mfma_f32_16x16x32_bf16(af0, bu, acc2[0][nt], 0, 0, 0);
        acc2[1][nt] = __builtin_amdgcn_mfma_f32_16x16x32_bf16(af1, bu, acc2[1][nt], 0, 0, 0);
      }
    }
    __builtin_amdgcn_s_setprio(0);
  };

  // ---- step loop: 4 lgkm-only barriers/step ----
  for (int s = 0; s < maxlen; s++) {
    #pragma unroll
    for (int i = 0; i < 2; i++)
      #pragma unroll
      for (int nt = 0; nt < 8; nt++) {
        acc2[i][nt][0] += b2v[i][0]; acc2[i][nt][1] += b2v[i][1];
        acc2[i][nt][2] += b2v[i][2]; acc2[i][nt][3] += b2v[i][3];
      }

    f32x4 acc1[2][8];
    #pragma unroll
    for (int i = 0; i < 2; i++)
      #pragma unroll
      for (int nt = 0; nt < 8; nt++) acc1[i][nt] = (f32x4){0.f, 0.f, 0.f, 0.f};
    MM1(0, acc1);
    UEPI(0, acc1);     // safe: prev step's uB readers done at barrier D
    bar_lds();         // A: uB(ch0) visible
    MM2(0);
    #pragma unroll
    for (int i = 0; i < 2; i++)
      #pragma unroll
      for (int nt = 0; nt < 8; nt++) acc1[i][nt] = (f32x4){0.f, 0.f, 0.f, 0.f};
    MM1(1, acc1);      // independent of uB -> overlaps mm2(ch0) region
    bar_lds();         // B: all mm2(ch0) uB reads done
    UEPI(1, acc1);
    bar_lds();         // C: uB(ch1) visible
    MM2(1);
    // ---- z epilogue: refresh zB, store alive cols ----
    #pragma unroll
    for (int i = 0; i < 2; i++) {
      const int cbase = (w * 2 + i) * 16 + quad * 4;
      const int ktz = cbase >> 5;
      const int gq  = (cbase >> 3) & 3;
      const int j0  = cbase & 7;
      #pragma unroll
      for (int nt = 0; nt < 8; nt++) {
        short4 zh;
        zh.x = f2bf(acc2[i][nt][0]); zh.y = f2bf(acc2[i][nt][1]);
        zh.z = f2bf(acc2[i][nt][2]); zh.w = f2bf(acc2[i][nt][3]);
        *(short4*)&zB[((ktz * 8 + nt) * 64 + m16 + 16 * gq) * 8 + j0] = zh;
        const int v = (nt & 1) * 16 + m16;
        if (v < Vv && s < len4[nt >> 1]) {
          const int o = sbase[nt >> 1] + cbase * TV + v + (s + 1) * Vv;
          out[o]          = acc2[i][nt][0];
          out[o + TV]     = acc2[i][nt][1];
          out[o + 2 * TV] = acc2[i][nt][2];
          out[o + 3 * TV] = acc2[i][nt][3];
        }
      }
    }
    bar_lds();         // D: zB ready for next step
  }
}

extern "C" void kernel_launch(void* const* d_in, const int* in_sizes, int n_in,
                              void* d_out, int out_size, void* d_ws, size_t ws_size,
                              hipStream_t stream) {
  const float* h_ptr = (const float*)d_in[0];
  const float* W1    = (const float*)d_in[1];
  const float* b1    = (const float*)d_in[2];
  const float* W2    = (const float*)d_in[3];
  const float* b2    = (const float*)d_in[4];
  const float* tf    = (const float*)d_in[5];
  float* out = (float*)d_out;

  short* a1p  = (short*)d_ws;            // 256 KB
  short* a2p  = a1p + 131072;            // 256 KB
  int* sorted = (int*)(a2p + 131072);    // 16 KB
  int* hdr    = sorted + MAXCH;          // 16 B

  prep_kernel<<<1025, 256, 0, stream>>>(W1, W2, tf, a1p, a2p, sorted, hdr);
  group_kernel<<<NGRID, 512, 0, stream>>>(h_ptr, b1, b2, a1p, a2p, sorted, hdr ? out : out);
}

// Round 7
// 375.739 us; speedup vs baseline: 1.9183x; 1.3210x over previous
//
#include <hip/hip_runtime.h>
#include <hip/hip_bf16.h>
#include <math.h>

// ODE Euler solver — R10: R9 with the ring-prefetch race fixed.
// R9 failed absmax 0.328: the `live` guard suppressed the next-step prefetch
// at tiles 30/31 of each chain's FINAL step, leaving only 4 outstanding VMEM
// ops -> s_waitcnt vmcnt(4) returned immediately -> ds_read saw the slot's
// previous occupant (tile 26/27 weights) -> last timestep of every chain had
// two wrong MM2 k-tiles. Fix: ISSUE unconditionally (wrap re-issues tiles 0,1;
// step-invariant addresses, harmless) so the vmcnt(4) ledger is exact at every
// iteration. Everything else byte-identical to R9.
// Theory under test (fits R3/R4/R8): wall = longest-chain x per-step time;
// per-step dominated by the latency-exposed 512KB/step weight re-stream.
// R10 pipelines it: global_load_lds into a per-wave 4-slot ring, depth 2,
// counted vmcnt(4) (never 0), stream crosses lgkm-only barriers and steps.

using bf16x8 = __attribute__((ext_vector_type(8))) short;   // 8 bf16
using f32x4  = __attribute__((ext_vector_type(4))) float;   // 4 fp32 acc

constexpr int Bb = 64, Cc = 256, Tt = 64, Vv = 25, Hh = 512;
constexpr int TV = Tt * Vv;              // 1600
constexpr int MAXCH = Bb * (Tt - 1);     // 4032
constexpr int NGRID = 2496;              // >= worst-case n1+npair (~2420)
constexpr int NTMAX = 4;                 // LDS stride in n-tiles

__device__ __forceinline__ short f2bf(float x) {
  union { float f; unsigned u; } v; v.f = x;
  unsigned r = v.u + 0x7FFFu + ((v.u >> 16) & 1u);
  return (short)(r >> 16);
}
__device__ __forceinline__ float fast_tanh(float x) {
  float e = __expf(2.f * x);
  return 1.f - 2.f * __builtin_amdgcn_rcpf(e + 1.f);
}
// lgkm-only barrier: LDS deps drained, global loads/stores stay in flight.
__device__ __forceinline__ void bar_lds() {
  asm volatile("s_waitcnt lgkmcnt(0)" ::: "memory");
  __builtin_amdgcn_s_barrier();
  asm volatile("" ::: "memory");
}
// 16B/lane global->LDS DMA. LDS dest = base + lane*16 (wave-uniform base).
__device__ __forceinline__ void gl2lds16(const short* g, short* l) {
  __builtin_amdgcn_global_load_lds(
      (const __attribute__((address_space(1))) void*)g,
      (__attribute__((address_space(3))) void*)l, 16, 0, 0);
}

// ---- fused prepack (blocks 0..1023) + plan (block 1024) ----
// A-frag (16x16x32): lane holds A[m=lane&15][k=(lane>>4)*8+j].
// a1p: A=W1^T (M=H: 32 mt, K=C: 8 kt):  idx ((kt*32+mt)*64+lane)*8+j
// a2p: A=W2^T (M=C: 16 mt, K=H: 16 kt): idx ((kt*16+mt)*64+lane)*8+j
__global__ void prep_kernel(const float* __restrict__ W1,
                            const float* __restrict__ W2,
                            const float* __restrict__ tf,
                            short* __restrict__ a1p,
                            short* __restrict__ a2p,
                            int* __restrict__ sorted,
                            int* __restrict__ hdr) {
  if (blockIdx.x < 1024) {
    int idx = blockIdx.x * 256 + threadIdx.x;
    if (idx < 131072) {
      int j = idx & 7, lane = (idx >> 3) & 63, mt = (idx >> 9) & 31, kt = idx >> 14;
      int h = mt * 16 + (lane & 15);
      int c = kt * 32 + (lane >> 4) * 8 + j;
      a1p[idx] = f2bf(W1[c * Hh + h]);
    } else {
      int i2 = idx - 131072;
      int j = i2 & 7, lane = (i2 >> 3) & 63, mt = (i2 >> 9) & 15, kt = i2 >> 13;
      int cm = mt * 16 + (lane & 15);
      int hk = kt * 32 + (lane >> 4) * 8 + j;
      a2p[i2] = f2bf(W2[hk * Cc + cm]);
    }
    return;
  }
  __shared__ int cnt[64];
  __shared__ int ofs[64];
  int tid = threadIdx.x;
  if (tid < 64) cnt[tid] = 0;
  for (int i = tid; i < MAXCH; i += 256) sorted[i] = 0;
  __syncthreads();
  if (tid < Bb) {
    int b = tid, prev = 0;
    for (int t = 1; t <= 62; t++)
      if (tf[t * Bb + b] >= 0.5f) { atomicAdd(&cnt[t - prev], 1); prev = t; }
    atomicAdd(&cnt[63 - prev], 1);
  }
  __syncthreads();
  if (tid == 0) {
    int acc = 0;
    for (int l = 63; l >= 1; l--) { ofs[l] = acc; acc += cnt[l]; }
    int n1 = 0;
    for (int l = 5; l <= 63; l++) n1 += cnt[l];
    hdr[0] = n1;                      // solos (len>=5)
    hdr[1] = (acc - n1 + 1) >> 1;     // pairs covering the rest
    hdr[2] = acc; hdr[3] = 0;
  }
  __syncthreads();
  if (tid < Bb) {
    int b = tid, prev = 0;
    for (int t = 1; t <= 62; t++) {
      if (tf[t * Bb + b] >= 0.5f) {
        int len = t - prev;
        int p = atomicAdd(&ofs[len], 1);
        sorted[p] = b | (prev << 6) | (len << 12);
        prev = t;
      }
    }
    int len = 63 - prev;
    int p = atomicAdd(&ofs[len], 1);
    sorted[p] = b | (prev << 6) | (len << 12);
  }
}

// LDS B-frag order (stride NTMAX):
// elem(k,n) at ((ktile*NTMAX + nt)*64 + (n&15) + 16*((k&31)>>3))*8 + (k&7)
template<int NCH>
__device__ __forceinline__ void run_group(
    int start,
    const float* __restrict__ hsrc, const float* __restrict__ b1,
    const float* __restrict__ b2,   const short* __restrict__ a1p,
    const short* __restrict__ a2p,  const int* __restrict__ sorted,
    float* __restrict__ out, short* __restrict__ zB, short* __restrict__ uB,
    short* __restrict__ wA) {
  constexpr int NTA = NCH * 2;                  // n-tiles (16 cols each)
  const int tid  = threadIdx.x;
  const int lane = tid & 63;
  const int w    = tid >> 6;                    // 0..7
  const int m16  = lane & 15;
  const int quad = lane >> 4;
  short* wv = wA + w * 4096;                    // 4 slots x 2KB per wave

  int meta[NCH], len[NCH], sbase[NCH], t0s[NCH];
  #pragma unroll
  for (int j = 0; j < NCH; j++) {
    meta[j]  = sorted[start + j];               // block-uniform -> s_load
    len[j]   = (meta[j] >> 12) & 63;
    t0s[j]   = (meta[j] >> 6) & 63;
    sbase[j] = (meta[j] & 63) * Cc * TV + t0s[j] * Vv;
  }
  const int maxlen = len[0];                    // sorted desc

  f32x4 acc2[2][NTA];                           // fp32 master state

  // ---- init: z0 = h[b,:,t0,:]; write zB in B-frag order ----
  #pragma unroll
  for (int i = 0; i < 2; i++) {
    const int cbase = (w * 2 + i) * 16 + quad * 4;    // 0..255, mult of 4
    const int ktz = cbase >> 5;
    const int gq  = (cbase >> 3) & 3;
    const int j0  = cbase & 7;
    #pragma unroll
    for (int nt = 0; nt < NTA; nt++) {
      const int j  = nt >> 1;
      const int v  = (nt & 1) * 16 + m16;
      const bool valid = (len[j] > 0) && (v < Vv);
      const int hb = sbase[j] + cbase * TV + v;
      f32x4 z;
      #pragma unroll
      for (int r = 0; r < 4; r++)
        z[r] = valid ? __builtin_nontemporal_load(&hsrc[hb + r * TV]) : 0.f;
      acc2[i][nt] = z;
      short4 zh;
      zh.x = f2bf(z[0]); zh.y = f2bf(z[1]); zh.z = f2bf(z[2]); zh.w = f2bf(z[3]);
      *(short4*)&zB[((ktz * NTMAX + nt) * 64 + m16 + 16 * gq) * 8 + j0] = zh;
      if (valid && t0s[j] == 0) {
        #pragma unroll
        for (int r = 0; r < 4; r++)
          __builtin_nontemporal_store(z[r], &out[hb + r * TV]);
      }
    }
  }

  // Weight tile stream: step = 32 tiles (ph0=MM1c0, ph1=MM2c0, ph2=MM1c1,
  // ph3=MM2c1), 2KB/tile/wave, 4-slot ring (32%4==0 -> slot=tile&3 static),
  // prefetch depth 2, addresses step-invariant.
  auto ISSUE = [&](int tile) {
    const int kt = tile & 7;
    const short* gp;
    switch (tile >> 3) {
      case 0:  gp = a1p + ((kt * 32 +      w * 2) * 64 + lane) * 8; break;
      case 1:  gp = a2p + (((     kt) * 16 + w * 2) * 64 + lane) * 8; break;
      case 2:  gp = a1p + ((kt * 32 + 16 + w * 2) * 64 + lane) * 8; break;
      default: gp = a2p + (((8 +  kt) * 16 + w * 2) * 64 + lane) * 8; break;
    }
    short* lp = wv + (tile & 3) * 1024;
    gl2lds16(gp, lp);             // mt0 fragment (1KB)
    gl2lds16(gp + 512, lp + 512); // mt1 fragment (1KB)
  };

  // prologue: prime the ring
  ISSUE(0);
  ISSUE(1);
  bar_lds();                     // zB visible (lgkm only; DMA stays in flight)

  // step-invariant b2 bias in registers
  f32x4 b2v[2];
  #pragma unroll
  for (int i = 0; i < 2; i++) {
    const float4 t = *(const float4*)(b2 + (w * 2 + i) * 16 + quad * 4);
    b2v[i] = (f32x4){t.x, t.y, t.z, t.w};
  }

  for (int s = 0; s < maxlen; s++) {
    // One MFMA phase: consume tiles ph*8..ph*8+7 from the ring.
    auto MMPH = [&](int ph, f32x4 (&acc)[2][NTA], const short* Bp) {
      #pragma unroll
      for (int kt = 0; kt < 8; kt++) {
        const int tile = ph * 8 + kt;
        __builtin_amdgcn_sched_barrier(0);  // pin iter order
        // UNCONDITIONAL prefetch (R9 bug fix): keeps exactly {t,t+1,t+2} in
        // flight at the wait below for EVERY iteration incl. the final
        // step's tiles 30/31 (wrap re-issues tiles 0,1 — step-invariant
        // addresses, harmless; R9's guard left 4 ops -> vmcnt(4) passed
        // before tile t landed -> stale slot on every chain's last step).
        ISSUE((tile + 2) & 31);
        asm volatile("s_waitcnt vmcnt(4)" ::: "memory");  // tile t landed;
                                                          // 2 tiles in flight
        const short* wp = wv + (tile & 3) * 1024 + lane * 8;
        bf16x8 af0 = *(const bf16x8*)wp;
        bf16x8 af1 = *(const bf16x8*)(wp + 512);
        #pragma unroll
        for (int nt = 0; nt < NTA; nt++) {
          bf16x8 bb = *(const bf16x8*)&Bp[((kt * NTMAX + nt) * 64 + lane) * 8];
          acc[0][nt] = __builtin_amdgcn_mfma_f32_16x16x32_bf16(af0, bb, acc[0][nt], 0, 0, 0);
          acc[1][nt] = __builtin_amdgcn_mfma_f32_16x16x32_bf16(af1, bb, acc[1][nt], 0, 0, 0);
        }
      }
    };
    auto UEPI = [&](int chunk, f32x4 (&a1)[2][NTA]) {
      #pragma unroll
      for (int i = 0; i < 2; i++) {
        const int hl  = (w * 2 + i) * 16 + quad * 4;   // chunk-local h
        const int ktl = hl >> 5;
        const int gq  = (hl >> 3) & 3;
        const int j0  = hl & 7;
        const float4 b1v = *(const float4*)(b1 + chunk * 256 + hl);
        #pragma unroll
        for (int nt = 0; nt < NTA; nt++) {
          short4 up;
          up.x = f2bf(fast_tanh(a1[i][nt][0] + b1v.x));
          up.y = f2bf(fast_tanh(a1[i][nt][1] + b1v.y));
          up.z = f2bf(fast_tanh(a1[i][nt][2] + b1v.z));
          up.w = f2bf(fast_tanh(a1[i][nt][3] + b1v.w));
          *(short4*)&uB[((ktl * NTMAX + nt) * 64 + m16 + 16 * gq) * 8 + j0] = up;
        }
      }
    };

    #pragma unroll
    for (int i = 0; i < 2; i++)
      #pragma unroll
      for (int nt = 0; nt < NTA; nt++) {
        acc2[i][nt][0] += b2v[i][0]; acc2[i][nt][1] += b2v[i][1];
        acc2[i][nt][2] += b2v[i][2]; acc2[i][nt][3] += b2v[i][3];
      }

    f32x4 acc1[2][NTA];
    #pragma unroll
    for (int i = 0; i < 2; i++)
      #pragma unroll
      for (int nt = 0; nt < NTA; nt++) acc1[i][nt] = (f32x4){0.f, 0.f, 0.f, 0.f};
    MMPH(0, acc1, zB);     // MM1 chunk0: tiles 0..7
    UEPI(0, acc1);
    bar_lds();             // A: uB(c0) visible
    MMPH(1, acc2, uB);     // MM2 chunk0: tiles 8..15
    #pragma unroll
    for (int i = 0; i < 2; i++)
      #pragma unroll
      for (int nt = 0; nt < NTA; nt++) acc1[i][nt] = (f32x4){0.f, 0.f, 0.f, 0.f};
    MMPH(2, acc1, zB);     // MM1 chunk1: tiles 16..23
    bar_lds();             // B: all uB(c0) reads done
    UEPI(1, acc1);
    bar_lds();             // C: uB(c1) visible
    MMPH(3, acc2, uB);     // MM2 chunk1: tiles 24..31
    // ---- z epilogue: refresh zB, store alive cols (nontemporal) ----
    #pragma unroll
    for (int i = 0; i < 2; i++) {
      const int cbase = (w * 2 + i) * 16 + quad * 4;
      const int ktz = cbase >> 5;
      const int gq  = (cbase >> 3) & 3;
      const int j0  = cbase & 7;
      #pragma unroll
      for (int nt = 0; nt < NTA; nt++) {
        short4 zh;
        zh.x = f2bf(acc2[i][nt][0]); zh.y = f2bf(acc2[i][nt][1]);
        zh.z = f2bf(acc2[i][nt][2]); zh.w = f2bf(acc2[i][nt][3]);
        *(short4*)&zB[((ktz * NTMAX + nt) * 64 + m16 + 16 * gq) * 8 + j0] = zh;
        const int v = (nt & 1) * 16 + m16;
        if (v < Vv && s < len[nt >> 1]) {
          const int o = sbase[nt >> 1] + cbase * TV + v + (s + 1) * Vv;
          __builtin_nontemporal_store(acc2[i][nt][0], &out[o]);
          __builtin_nontemporal_store(acc2[i][nt][1], &out[o + TV]);
          __builtin_nontemporal_store(acc2[i][nt][2], &out[o + 2 * TV]);
          __builtin_nontemporal_store(acc2[i][nt][3], &out[o + 3 * TV]);
        }
      }
    }
    bar_lds();             // D: zB ready for next step
  }
}

__global__ __launch_bounds__(512, 1) void group_kernel(
    const float* __restrict__ hsrc, const float* __restrict__ b1,
    const float* __restrict__ b2,   const short* __restrict__ a1p,
    const short* __restrict__ a2p,  const int* __restrict__ sorted,
    const int* __restrict__ hdr,    float* __restrict__ out) {
  __shared__ __align__(16) short zB[8 * NTMAX * 64 * 8];   // 32 KB
  __shared__ __align__(16) short uB[8 * NTMAX * 64 * 8];   // 32 KB
  __shared__ __align__(16) short wA[8 * 4 * 1024];         // 64 KB weight ring

  const int n1 = hdr[0], npair = hdr[1];
  const int bi = blockIdx.x;
  if (bi < n1) {
    run_group<1>(bi, hsrc, b1, b2, a1p, a2p, sorted, out, zB, uB, wA);
  } else if (bi < n1 + npair) {
    run_group<2>(n1 + (bi - n1) * 2, hsrc, b1, b2, a1p, a2p, sorted, out, zB, uB, wA);
  }
}

extern "C" void kernel_launch(void* const* d_in, const int* in_sizes, int n_in,
                              void* d_out, int out_size, void* d_ws, size_t ws_size,
                              hipStream_t stream) {
  const float* h_ptr = (const float*)d_in[0];
  const float* W1    = (const float*)d_in[1];
  const float* b1    = (const float*)d_in[2];
  const float* W2    = (const float*)d_in[3];
  const float* b2    = (const float*)d_in[4];
  const float* tf    = (const float*)d_in[5];
  float* out = (float*)d_out;

  short* a1p  = (short*)d_ws;            // 256 KB
  short* a2p  = a1p + 131072;            // 256 KB
  int* sorted = (int*)(a2p + 131072);    // 16 KB
  int* hdr    = sorted + MAXCH;          // 16 B

  prep_kernel<<<1025, 256, 0, stream>>>(W1, W2, tf, a1p, a2p, sorted, hdr);
  group_kernel<<<NGRID, 512, 0, stream>>>(h_ptr, b1, b2, a1p, a2p, sorted, hdr, out);
}

// Round 8
// 353.249 us; speedup vs baseline: 2.0404x; 1.0637x over previous
//
#include <hip/hip_runtime.h>
#include <hip/hip_bf16.h>
#include <math.h>

// ODE Euler solver — R11: unpin the scheduler, kill the store-drain.
// R10 (ring, verified correct) = 193us ~= plateau. Counters: LDS pipe ~50%
// busy, VALU 18%, MFMA 14% -> still serialization-bound. Two self-inflicted
// serializers removed vs R10:
//  1. sched_barrier(0) per k-tile (32/step) = the m141 anti-pattern (-42% in
//     learn_hip). Redundant for correctness: "memory"-clobber asm waits pin
//     ISSUE-vs-read order; LDS store/load aliasing pins ring slot reuse.
//  2. Store-drain: vm ops retire IN ORDER and stores share vmcnt with the
//     ring. Every step-start vmcnt(4) drained the prior epilogue's >=16
//     stores. Fix: (a) plain stores (retire at L2, not HBM); (b) ledger-exact
//     relaxed waits at step-start kt0/kt1: younger-than-t0 >= 16st+2 ->
//     vmcnt(18); younger-than-t1 >= 20 -> vmcnt(20). Only for s>0 (step 0
//     has no prior stores -> tight vmcnt(4)).

using bf16x8 = __attribute__((ext_vector_type(8))) short;   // 8 bf16
using f32x4  = __attribute__((ext_vector_type(4))) float;   // 4 fp32 acc

constexpr int Bb = 64, Cc = 256, Tt = 64, Vv = 25, Hh = 512;
constexpr int TV = Tt * Vv;              // 1600
constexpr int MAXCH = Bb * (Tt - 1);     // 4032
constexpr int NGRID = 2496;              // >= worst-case n1+npair
constexpr int NTMAX = 4;                 // LDS stride in n-tiles

__device__ __forceinline__ short f2bf(float x) {
  union { float f; unsigned u; } v; v.f = x;
  unsigned r = v.u + 0x7FFFu + ((v.u >> 16) & 1u);
  return (short)(r >> 16);
}
__device__ __forceinline__ float fast_tanh(float x) {
  float e = __expf(2.f * x);
  return 1.f - 2.f * __builtin_amdgcn_rcpf(e + 1.f);
}
// lgkm-only barrier: LDS deps drained, global loads/stores stay in flight.
__device__ __forceinline__ void bar_lds() {
  asm volatile("s_waitcnt lgkmcnt(0)" ::: "memory");
  __builtin_amdgcn_s_barrier();
  asm volatile("" ::: "memory");
}
// 16B/lane global->LDS DMA. LDS dest = base + lane*16 (wave-uniform base).
__device__ __forceinline__ void gl2lds16(const short* g, short* l) {
  __builtin_amdgcn_global_load_lds(
      (const __attribute__((address_space(1))) void*)g,
      (__attribute__((address_space(3))) void*)l, 16, 0, 0);
}

// ---- fused prepack (blocks 0..1023) + plan (block 1024) ----
// A-frag (16x16x32): lane holds A[m=lane&15][k=(lane>>4)*8+j].
// a1p: A=W1^T (M=H: 32 mt, K=C: 8 kt):  idx ((kt*32+mt)*64+lane)*8+j
// a2p: A=W2^T (M=C: 16 mt, K=H: 16 kt): idx ((kt*16+mt)*64+lane)*8+j
__global__ void prep_kernel(const float* __restrict__ W1,
                            const float* __restrict__ W2,
                            const float* __restrict__ tf,
                            short* __restrict__ a1p,
                            short* __restrict__ a2p,
                            int* __restrict__ sorted,
                            int* __restrict__ hdr) {
  if (blockIdx.x < 1024) {
    int idx = blockIdx.x * 256 + threadIdx.x;
    if (idx < 131072) {
      int j = idx & 7, lane = (idx >> 3) & 63, mt = (idx >> 9) & 31, kt = idx >> 14;
      int h = mt * 16 + (lane & 15);
      int c = kt * 32 + (lane >> 4) * 8 + j;
      a1p[idx] = f2bf(W1[c * Hh + h]);
    } else {
      int i2 = idx - 131072;
      int j = i2 & 7, lane = (i2 >> 3) & 63, mt = (i2 >> 9) & 15, kt = i2 >> 13;
      int cm = mt * 16 + (lane & 15);
      int hk = kt * 32 + (lane >> 4) * 8 + j;
      a2p[i2] = f2bf(W2[hk * Cc + cm]);
    }
    return;
  }
  __shared__ int cnt[64];
  __shared__ int ofs[64];
  int tid = threadIdx.x;
  if (tid < 64) cnt[tid] = 0;
  for (int i = tid; i < MAXCH; i += 256) sorted[i] = 0;
  __syncthreads();
  if (tid < Bb) {
    int b = tid, prev = 0;
    for (int t = 1; t <= 62; t++)
      if (tf[t * Bb + b] >= 0.5f) { atomicAdd(&cnt[t - prev], 1); prev = t; }
    atomicAdd(&cnt[63 - prev], 1);
  }
  __syncthreads();
  if (tid == 0) {
    int acc = 0;
    for (int l = 63; l >= 1; l--) { ofs[l] = acc; acc += cnt[l]; }
    int n1 = 0;
    for (int l = 5; l <= 63; l++) n1 += cnt[l];
    hdr[0] = n1;                      // solos (len>=5)
    hdr[1] = (acc - n1 + 1) >> 1;     // pairs covering the rest
    hdr[2] = acc; hdr[3] = 0;
  }
  __syncthreads();
  if (tid < Bb) {
    int b = tid, prev = 0;
    for (int t = 1; t <= 62; t++) {
      if (tf[t * Bb + b] >= 0.5f) {
        int len = t - prev;
        int p = atomicAdd(&ofs[len], 1);
        sorted[p] = b | (prev << 6) | (len << 12);
        prev = t;
      }
    }
    int len = 63 - prev;
    int p = atomicAdd(&ofs[len], 1);
    sorted[p] = b | (prev << 6) | (len << 12);
  }
}

// LDS B-frag order (stride NTMAX):
// elem(k,n) at ((ktile*NTMAX + nt)*64 + (n&15) + 16*((k&31)>>3))*8 + (k&7)
template<int NCH>
__device__ __forceinline__ void run_group(
    int start,
    const float* __restrict__ hsrc, const float* __restrict__ b1,
    const float* __restrict__ b2,   const short* __restrict__ a1p,
    const short* __restrict__ a2p,  const int* __restrict__ sorted,
    float* __restrict__ out, short* __restrict__ zB, short* __restrict__ uB,
    short* __restrict__ wA) {
  constexpr int NTA = NCH * 2;                  // n-tiles (16 cols each)
  const int tid  = threadIdx.x;
  const int lane = tid & 63;
  const int w    = tid >> 6;                    // 0..7
  const int m16  = lane & 15;
  const int quad = lane >> 4;
  short* wv = wA + w * 4096;                    // 4 slots x 2KB per wave

  int meta[NCH], len[NCH], sbase[NCH], t0s[NCH];
  #pragma unroll
  for (int j = 0; j < NCH; j++) {
    meta[j]  = sorted[start + j];               // block-uniform -> s_load
    len[j]   = (meta[j] >> 12) & 63;
    t0s[j]   = (meta[j] >> 6) & 63;
    sbase[j] = (meta[j] & 63) * Cc * TV + t0s[j] * Vv;
  }
  const int maxlen = len[0];                    // sorted desc

  f32x4 acc2[2][NTA];                           // fp32 master state

  // ---- init: z0 = h[b,:,t0,:]; write zB in B-frag order ----
  #pragma unroll
  for (int i = 0; i < 2; i++) {
    const int cbase = (w * 2 + i) * 16 + quad * 4;    // 0..255, mult of 4
    const int ktz = cbase >> 5;
    const int gq  = (cbase >> 3) & 3;
    const int j0  = cbase & 7;
    #pragma unroll
    for (int nt = 0; nt < NTA; nt++) {
      const int j  = nt >> 1;
      const int v  = (nt & 1) * 16 + m16;
      const bool valid = (len[j] > 0) && (v < Vv);
      const int hb = sbase[j] + cbase * TV + v;
      f32x4 z;
      #pragma unroll
      for (int r = 0; r < 4; r++)
        z[r] = valid ? __builtin_nontemporal_load(&hsrc[hb + r * TV]) : 0.f;
      acc2[i][nt] = z;
      short4 zh;
      zh.x = f2bf(z[0]); zh.y = f2bf(z[1]); zh.z = f2bf(z[2]); zh.w = f2bf(z[3]);
      *(short4*)&zB[((ktz * NTMAX + nt) * 64 + m16 + 16 * gq) * 8 + j0] = zh;
      if (valid && t0s[j] == 0) {
        #pragma unroll
        for (int r = 0; r < 4; r++) out[hb + r * TV] = z[r];
      }
    }
  }

  // Weight tile stream: step = 32 tiles (ph0=MM1c0, ph1=MM2c0, ph2=MM1c1,
  // ph3=MM2c1), 2KB/tile/wave, 4-slot ring (slot = tile&3), depth 2.
  auto ISSUE = [&](int tile) {
    const int kt = tile & 7;
    const short* gp;
    switch (tile >> 3) {
      case 0:  gp = a1p + ((kt * 32 +      w * 2) * 64 + lane) * 8; break;
      case 1:  gp = a2p + (((     kt) * 16 + w * 2) * 64 + lane) * 8; break;
      case 2:  gp = a1p + ((kt * 32 + 16 + w * 2) * 64 + lane) * 8; break;
      default: gp = a2p + (((8 +  kt) * 16 + w * 2) * 64 + lane) * 8; break;
    }
    short* lp = wv + (tile & 3) * 1024;
    gl2lds16(gp, lp);             // mt0 fragment (1KB)
    gl2lds16(gp + 512, lp + 512); // mt1 fragment (1KB)
  };

  // prologue: prime the ring
  ISSUE(0);
  ISSUE(1);
  bar_lds();                     // zB visible (lgkm only; DMA stays in flight)

  // step-invariant b2 bias in registers
  f32x4 b2v[2];
  #pragma unroll
  for (int i = 0; i < 2; i++) {
    const float4 t = *(const float4*)(b2 + (w * 2 + i) * 16 + quad * 4);
    b2v[i] = (f32x4){t.x, t.y, t.z, t.w};
  }

  for (int s = 0; s < maxlen; s++) {
    // One MFMA phase: consume tiles ph*8..ph*8+7 from the ring.
    // relax: step-start only (s>0) — prior epilogue's >=16 stores pad the
    // in-order vmcnt ledger: younger-than-t0 >= 18, younger-than-t1 >= 20.
    // (NO sched_barrier — m141: order-pinning defeats compiler scheduling.
    //  Ring safety holds: ISSUE/ds_read can't cross "memory" asm; LDS
    //  store-above-load reorder is blocked by aliasing.)
    auto MMPH = [&](int ph, f32x4 (&acc)[2][NTA], const short* Bp, bool relax) {
      #pragma unroll
      for (int kt = 0; kt < 8; kt++) {
        const int tile = ph * 8 + kt;
        ISSUE((tile + 2) & 31);   // unconditional: keeps ledger exact (R10 fix)
        if (relax && kt == 0)      asm volatile("s_waitcnt vmcnt(18)" ::: "memory");
        else if (relax && kt == 1) asm volatile("s_waitcnt vmcnt(20)" ::: "memory");
        else                       asm volatile("s_waitcnt vmcnt(4)"  ::: "memory");
        const short* wp = wv + (tile & 3) * 1024 + lane * 8;
        bf16x8 af0 = *(const bf16x8*)wp;
        bf16x8 af1 = *(const bf16x8*)(wp + 512);
        #pragma unroll
        for (int nt = 0; nt < NTA; nt++) {
          bf16x8 bb = *(const bf16x8*)&Bp[((kt * NTMAX + nt) * 64 + lane) * 8];
          acc[0][nt] = __builtin_amdgcn_mfma_f32_16x16x32_bf16(af0, bb, acc[0][nt], 0, 0, 0);
          acc[1][nt] = __builtin_amdgcn_mfma_f32_16x16x32_bf16(af1, bb, acc[1][nt], 0, 0, 0);
        }
      }
    };
    auto UEPI = [&](int chunk, f32x4 (&a1)[2][NTA]) {
      #pragma unroll
      for (int i = 0; i < 2; i++) {
        const int hl  = (w * 2 + i) * 16 + quad * 4;   // chunk-local h
        const int ktl = hl >> 5;
        const int gq  = (hl >> 3) & 3;
        const int j0  = hl & 7;
        const float4 b1v = *(const float4*)(b1 + chunk * 256 + hl);
        #pragma unroll
        for (int nt = 0; nt < NTA; nt++) {
          short4 up;
          up.x = f2bf(fast_tanh(a1[i][nt][0] + b1v.x));
          up.y = f2bf(fast_tanh(a1[i][nt][1] + b1v.y));
          up.z = f2bf(fast_tanh(a1[i][nt][2] + b1v.z));
          up.w = f2bf(fast_tanh(a1[i][nt][3] + b1v.w));
          *(short4*)&uB[((ktl * NTMAX + nt) * 64 + m16 + 16 * gq) * 8 + j0] = up;
        }
      }
    };

    #pragma unroll
    for (int i = 0; i < 2; i++)
      #pragma unroll
      for (int nt = 0; nt < NTA; nt++) {
        acc2[i][nt][0] += b2v[i][0]; acc2[i][nt][1] += b2v[i][1];
        acc2[i][nt][2] += b2v[i][2]; acc2[i][nt][3] += b2v[i][3];
      }

    f32x4 acc1[2][NTA];
    #pragma unroll
    for (int i = 0; i < 2; i++)
      #pragma unroll
      for (int nt = 0; nt < NTA; nt++) acc1[i][nt] = (f32x4){0.f, 0.f, 0.f, 0.f};
    MMPH(0, acc1, zB, s > 0);  // MM1 chunk0: tiles 0..7 (relaxed kt0/kt1)
    UEPI(0, acc1);
    bar_lds();                 // A: uB(c0) visible
    MMPH(1, acc2, uB, false);  // MM2 chunk0: tiles 8..15
    #pragma unroll
    for (int i = 0; i < 2; i++)
      #pragma unroll
      for (int nt = 0; nt < NTA; nt++) acc1[i][nt] = (f32x4){0.f, 0.f, 0.f, 0.f};
    MMPH(2, acc1, zB, false);  // MM1 chunk1: tiles 16..23
    bar_lds();                 // B: all uB(c0) reads done
    UEPI(1, acc1);
    bar_lds();                 // C: uB(c1) visible
    MMPH(3, acc2, uB, false);  // MM2 chunk1: tiles 24..31
    // ---- z epilogue: refresh zB, store alive cols (plain stores: retire
    // at L2, ~5x faster drain than nontemporal's HBM retirement) ----
    #pragma unroll
    for (int i = 0; i < 2; i++) {
      const int cbase = (w * 2 + i) * 16 + quad * 4;
      const int ktz = cbase >> 5;
      const int gq  = (cbase >> 3) & 3;
      const int j0  = cbase & 7;
      #pragma unroll
      for (int nt = 0; nt < NTA; nt++) {
        short4 zh;
        zh.x = f2bf(acc2[i][nt][0]); zh.y = f2bf(acc2[i][nt][1]);
        zh.z = f2bf(acc2[i][nt][2]); zh.w = f2bf(acc2[i][nt][3]);
        *(short4*)&zB[((ktz * NTMAX + nt) * 64 + m16 + 16 * gq) * 8 + j0] = zh;
        const int v = (nt & 1) * 16 + m16;
        if (v < Vv && s < len[nt >> 1]) {
          const int o = sbase[nt >> 1] + cbase * TV + v + (s + 1) * Vv;
          out[o]          = acc2[i][nt][0];
          out[o + TV]     = acc2[i][nt][1];
          out[o + 2 * TV] = acc2[i][nt][2];
          out[o + 3 * TV] = acc2[i][nt][3];
        }
      }
    }
    bar_lds();                 // D: zB ready for next step
  }
}

__global__ __launch_bounds__(512, 1) void group_kernel(
    const float* __restrict__ hsrc, const float* __restrict__ b1,
    const float* __restrict__ b2,   const short* __restrict__ a1p,
    const short* __restrict__ a2p,  const int* __restrict__ sorted,
    const int* __restrict__ hdr,    float* __restrict__ out) {
  __shared__ __align__(16) short zB[8 * NTMAX * 64 * 8];   // 32 KB
  __shared__ __align__(16) short uB[8 * NTMAX * 64 * 8];   // 32 KB
  __shared__ __align__(16) short wA[8 * 4 * 1024];         // 64 KB weight ring

  const int n1 = hdr[0], npair = hdr[1];
  const int bi = blockIdx.x;
  if (bi < n1) {
    run_group<1>(bi, hsrc, b1, b2, a1p, a2p, sorted, out, zB, uB, wA);
  } else if (bi < n1 + npair) {
    run_group<2>(n1 + (bi - n1) * 2, hsrc, b1, b2, a1p, a2p, sorted, out, zB, uB, wA);
  }
}

extern "C" void kernel_launch(void* const* d_in, const int* in_sizes, int n_in,
                              void* d_out, int out_size, void* d_ws, size_t ws_size,
                              hipStream_t stream) {
  const float* h_ptr = (const float*)d_in[0];
  const float* W1    = (const float*)d_in[1];
  const float* b1    = (const float*)d_in[2];
  const float* W2    = (const float*)d_in[3];
  const float* b2    = (const float*)d_in[4];
  const float* tf    = (const float*)d_in[5];
  float* out = (float*)d_out;

  short* a1p  = (short*)d_ws;            // 256 KB
  short* a2p  = a1p + 131072;            // 256 KB
  int* sorted = (int*)(a2p + 131072);    // 16 KB
  int* hdr    = sorted + MAXCH;          // 16 B

  prep_kernel<<<1025, 256, 0, stream>>>(W1, W2, tf, a1p, a2p, sorted, hdr);
  group_kernel<<<NGRID, 512, 0, stream>>>(h_ptr, b1, b2, a1p, a2p, sorted, hdr, out);
}